// Round 3
// baseline (189.902 us; speedup 1.0000x reference)
//
#include <hip/hip_runtime.h>
#include <hip/hip_bf16.h>
#include <math.h>

// VOCAB=50000, EMBED=256, MAXLEN=512, UNITS=32, F1=16, BATCH=512.
#define TT 512
#define BB 512
#define EE 256
#define UU 32
#define FF1 16
#define NWAVE 2048            // proj waves: 8/CU, 2/SIMD

// 2*log2(e): pre-scale factor so tanh needs no leading multiply.
#define TWO_LOG2E 2.8853900817779268f

__device__ __forceinline__ float rdlane(float v, int lane) {
    return __int_as_float(__builtin_amdgcn_readlane(__float_as_int(v), lane));
}

// v += value from lane (i - N) within the 16-lane DPP row (0 past row edge).
#define DPP_ADD(v, ctrl)                                                    \
    (v) += __int_as_float(__builtin_amdgcn_update_dpp(                      \
        0, __float_as_int(v), (ctrl), 0xf, 0xf, true))

// ---------------------------------------------------------------------------
// Kernel A: P[r][u] = (emb[r] @ Wx[:,u] + bias[u]) * 2*log2(e).
// DPP-reduce GEMV. v9: x loads widened to dwordx2 (8 instrs/row, 128B-wide
// unique per 16-lane group) with k-remap k = {2c,2c+1}+32*kk folded into the
// weight preload. DPP reduce unchanged (sum over c covers all 256 k).
// ---------------------------------------------------------------------------
__global__ __launch_bounds__(64) void proj_dpp(
    const float* __restrict__ emb, const float* __restrict__ Wx,
    const float* __restrict__ bias, float* __restrict__ P, int nrows)
{
    const int L = threadIdx.x;
    const int g = L >> 4;              // u-octet 0..3
    const int c = L & 15;              // k-lane 0..15
    const int wv = blockIdx.x;         // 0..NWAVE-1

    // ---- one-time coalesced w preload: w[kk][d][uu] = Wx[32kk+2c+d][g*8+uu]
    float w[8][2][8];
    #pragma unroll
    for (int kk = 0; kk < 8; ++kk) {
        #pragma unroll
        for (int d = 0; d < 2; ++d) {
            const int row = 32 * kk + 2 * c + d;
            const float4* src = (const float4*)(Wx + (size_t)row * UU + g * 8);
            float4 a = src[0], b = src[1];
            w[kk][d][0] = a.x; w[kk][d][1] = a.y; w[kk][d][2] = a.z; w[kk][d][3] = a.w;
            w[kk][d][4] = b.x; w[kk][d][5] = b.y; w[kk][d][6] = b.z; w[kk][d][7] = b.w;
        }
    }
    float bs[8];
    #pragma unroll
    for (int uu = 0; uu < 8; ++uu) bs[uu] = bias[g * 8 + uu];

    // rows handled by this wave: r = wv + NWAVE*i
    auto rowptr2 = [&](int i) {
        int r = wv + NWAVE * i;
        if (r >= nrows) r = nrows - 1;             // clamped dummy
        return (const float2*)(emb + (size_t)r * EE);
    };

    float2 xA[8], xB[8];
    {
        const float2* rp = rowptr2(0);
        #pragma unroll
        for (int kk = 0; kk < 8; ++kk) xA[kk] = rp[kk * 16 + c];
    }

    const int NI = (nrows - 1 - wv) / NWAVE + 1;   // #valid rows (wv < nrows)

    for (int i = 0; i < NI; ++i) {
        // prefetch next row (clamped at tail): 8 x 8B, 128B-wide per group
        {
            const float2* rp = rowptr2(i + 1 < NI ? i + 1 : i);
            #pragma unroll
            for (int kk = 0; kk < 8; ++kk) xB[kk] = rp[kk * 16 + c];
        }

        // partials for this lane's 16 k's x 8 u's
        float p[8];
        #pragma unroll
        for (int uu = 0; uu < 8; ++uu) p[uu] = 0.f;
        #pragma unroll
        for (int kk = 0; kk < 8; ++kk) {
            const float2 xp = xA[kk];
            #pragma unroll
            for (int uu = 0; uu < 8; ++uu)
                p[uu] = fmaf(xp.x, w[kk][0][uu], p[uu]);
            #pragma unroll
            for (int uu = 0; uu < 8; ++uu)
                p[uu] = fmaf(xp.y, w[kk][1][uu], p[uu]);
        }

        // reduce over the 16 c-lanes (DPP row-of-16); lane c==15 holds sums
        #pragma unroll
        for (int uu = 0; uu < 8; ++uu) {
            DPP_ADD(p[uu], 0x111);   // row_shr:1
            DPP_ADD(p[uu], 0x112);   // row_shr:2
            DPP_ADD(p[uu], 0x114);   // row_shr:4
            DPP_ADD(p[uu], 0x118);   // row_shr:8
        }

        if (c == 15) {
            const int r = wv + NWAVE * i;
            float4 o0, o1;
            o0.x = (p[0] + bs[0]) * TWO_LOG2E;
            o0.y = (p[1] + bs[1]) * TWO_LOG2E;
            o0.z = (p[2] + bs[2]) * TWO_LOG2E;
            o0.w = (p[3] + bs[3]) * TWO_LOG2E;
            o1.x = (p[4] + bs[4]) * TWO_LOG2E;
            o1.y = (p[5] + bs[5]) * TWO_LOG2E;
            o1.z = (p[6] + bs[6]) * TWO_LOG2E;
            o1.w = (p[7] + bs[7]) * TWO_LOG2E;
            float4* dst = (float4*)(P + (size_t)r * UU + g * 8);
            dst[0] = o0; dst[1] = o1;
        }

        #pragma unroll
        for (int kk = 0; kk < 8; ++kk) xA[kk] = xB[kk];
    }
}

// ---------------------------------------------------------------------------
// Kernel B v9: readlane scan, r-broadcast fold + half-wave exec + 8/8 dbuf.
// Recurrence rewritten around r = rcp(exp2(a')+1)  (h = 1 - 2r):
//   a'_u(t+1) = P'[t+1][u] + S_u + sum_k r_k * wr_ku
// with wr = -2*wh (wh = 2log2e*Wh col), S_u = sum_k wh_ku.  The +S_u rides on
// the x-prefetch (off-chain); the old fma(-2,r,1) leaves the serial chain.
// Initial r = 0.5 (h=0).  h materialized once post-loop for the heads.
// Scan+heads run under if(L<32): upper half was redundant; if HW skips
// inactive 32-lane halves every VALU op halves its issue cost (else no-op).
// 8/8 double-buffered unroll kills the xr rotation movs.
// ---------------------------------------------------------------------------
__global__ __launch_bounds__(64) void scan_heads(
    const int* __restrict__ tokens, const float* __restrict__ P,
    const float* __restrict__ Wh,
    const float* __restrict__ W1, const float* __restrict__ b1,
    const float* __restrict__ W2, const float* __restrict__ b2,
    float* __restrict__ out)
{
    __shared__ float xs[TT * UU];      // 512 rows x 128 B = 64 KB

    const int L = threadIdx.x;
    const int u = L & 31;
    const int b = blockIdx.x;
    const int* trow = tokens + b * TT;

    // wr[k] = -2 * (Wh[k][u] * 2log2e); S = sum_k (Wh[k][u] * 2log2e)
    float wr[UU];
    float S = 0.f;
    #pragma unroll
    for (int k = 0; k < UU; ++k) {
        float whk = Wh[k * UU + u] * TWO_LOG2E;
        S += whk;
        wr[k] = -2.0f * whk;
    }

    // ---- gather phase: 64 global_load_lds instrs, 8 tokens each ----
    const int sub = L >> 3;            // token-within-group
    const int q   = L & 7;             // 16-B chunk within the 128-B row
    for (int c = 0; c < 8; ++c) {
        int tk8[8];
        #pragma unroll
        for (int i = 0; i < 8; ++i)
            tk8[i] = trow[c * 64 + i * 8 + sub];
        #pragma unroll
        for (int i = 0; i < 8; ++i) {
            const float* src = P + (size_t)tk8[i] * UU + q * 4;
            float* dst = xs + (c * 64 + i * 8) * UU;    // wave-uniform base
            __builtin_amdgcn_global_load_lds(
                (const __attribute__((address_space(1))) void*)src,
                (__attribute__((address_space(3))) void*)dst, 16, 0, 0);
        }
    }
    __syncthreads();   // drains vmcnt: all LDS rows resident

    if (L < 32) {
        // ---- scan: pure LDS + VALU, lower half only ----
        float xA[8], xB[8];
        #pragma unroll
        for (int j = 0; j < 8; ++j) xA[j] = xs[j * UU + u] + S;

        float r = 0.5f;                // h = 0  =>  r = 0.5

        // one step: a' = x(+S) + sum_k r_k * wr_k ; r' = rcp(exp2(a')+1)
        auto step = [&](float rc, float x) -> float {
            float rv[UU];
            #pragma unroll
            for (int k = 0; k < UU; ++k) rv[k] = rdlane(rc, k);

            float a0 = fmaf(rv[0], wr[0], x);
            float a1 = rv[1] * wr[1];
            float a2 = rv[2] * wr[2];
            float a3 = rv[3] * wr[3];
            #pragma unroll
            for (int k = 4; k < UU; k += 4) {
                a0 = fmaf(rv[k],     wr[k],     a0);
                a1 = fmaf(rv[k + 1], wr[k + 1], a1);
                a2 = fmaf(rv[k + 2], wr[k + 2], a2);
                a3 = fmaf(rv[k + 3], wr[k + 3], a3);
            }
            float e = __builtin_amdgcn_exp2f((a0 + a1) + (a2 + a3));
            return __builtin_amdgcn_rcpf(e + 1.0f);
        };

        for (int t = 0; t < TT; t += 16) {
            #pragma unroll
            for (int j = 0; j < 8; ++j)
                xB[j] = xs[((t + 8 + j) & (TT - 1)) * UU + u] + S;
            #pragma unroll
            for (int j = 0; j < 8; ++j) r = step(r, xA[j]);
            #pragma unroll
            for (int j = 0; j < 8; ++j)
                xA[j] = xs[((t + 16 + j) & (TT - 1)) * UU + u] + S;
            #pragma unroll
            for (int j = 0; j < 8; ++j) r = step(r, xB[j]);
        }

        float h = fmaf(-2.0f, r, 1.0f);   // materialize h once for the heads

        // ---- fused heads (once; readlane-only; h in lanes 0-31) ----
        const int j = L & 15;
        float s = b1[j];
        #pragma unroll
        for (int k = 0; k < UU; ++k) {
            float hk = rdlane(h, k);
            s = fmaf(hk, W1[k * FF1 + j], s);
        }
        float z = b2[0];
        #pragma unroll
        for (int jj = 0; jj < FF1; ++jj) {
            float yj = rdlane(s, jj);
            z = fmaf(yj, W2[jj], z);
        }
        if (L == 0) {
            float e = __builtin_amdgcn_exp2f(-z * 1.4426950408889634f); // e^{-z}
            out[b] = __builtin_amdgcn_rcpf(1.0f + e);
        }
    }
}

// ---------------------------------------------------------------------------
extern "C" void kernel_launch(void* const* d_in, const int* in_sizes, int n_in,
                              void* d_out, int out_size, void* d_ws, size_t ws_size,
                              hipStream_t stream) {
    const int*   tokens = (const int*)  d_in[0];
    const float* emb    = (const float*)d_in[1];
    const float* Wx     = (const float*)d_in[2];
    const float* Wh     = (const float*)d_in[3];
    const float* bias   = (const float*)d_in[4];
    const float* W1     = (const float*)d_in[5];
    const float* b1     = (const float*)d_in[6];
    const float* W2     = (const float*)d_in[7];
    const float* b2     = (const float*)d_in[8];
    float* out = (float*)d_out;

    const int vocab = in_sizes[1] / EE;        // 50000
    float* P = (float*)d_ws;                   // vocab*32*4 = 6.4 MB

    // A: 2048 single-wave blocks, ~25 rows each (8 waves/CU)
    proj_dpp<<<dim3(NWAVE), dim3(64), 0, stream>>>(
        emb, Wx, bias, P, vocab);

    // B: 1 batch row per wave -> 512 blocks x 64 threads (2 blocks/CU)
    scan_heads<<<dim3(BB), dim3(64), 0, stream>>>(
        tokens, P, Wh, W1, b1, W2, b2, out);
}